// Round 16
// baseline (328.870 us; speedup 1.0000x reference)
//
#include <hip/hip_runtime.h>
#include <type_traits>

typedef unsigned short ushort_t;
typedef unsigned int   uint_t;
typedef __attribute__((ext_vector_type(8))) short bf16x8;
typedef __attribute__((ext_vector_type(4))) float f32x4;

constexpr int Bn = 4, Tn = 1024, Cn = 2048, NH = 16, HS = 128;
constexpr int NLQ = 1536, NLKV = 512, DHR = 64;
constexpr int BT = Bn * Tn;
constexpr int KLD = 640;                  // kfull leading dim (512 ckv + 64 kr + 64 pad)
constexpr float ATT_SCALE = 0.07216878364870323f; // 1/sqrt(192)
constexpr float LOG2E = 1.4426950408889634f;

__device__ __forceinline__ ushort_t f2bf(float f) {
    uint_t u = __float_as_uint(f);
    u += 0x7fffu + ((u >> 16) & 1u);   // RNE
    return (ushort_t)(u >> 16);
}

__device__ __forceinline__ void gload_lds16(const void* g, void* l) {
    __builtin_amdgcn_global_load_lds(
        (__attribute__((address_space(1))) void*)g,
        (__attribute__((address_space(3))) void*)l, 16, 0, 0);
}

// Pipeline sync (raw barrier, counted vmcnt). N = loads/wave allowed in flight.
__device__ __forceinline__ void pipe_wait4(bool last) {
    if (last) asm volatile("s_waitcnt vmcnt(0)" ::: "memory");
    else      asm volatile("s_waitcnt vmcnt(4)" ::: "memory");
    __builtin_amdgcn_s_barrier();
    asm volatile("" ::: "memory");
}
__device__ __forceinline__ void pipe_wait6(bool last) {
    if (last) asm volatile("s_waitcnt vmcnt(0)" ::: "memory");
    else      asm volatile("s_waitcnt vmcnt(6)" ::: "memory");
    __builtin_amdgcn_s_barrier();
    asm volatile("" ::: "memory");
}

// LDS swizzle (rule #21): linear gload_lds dest + inverse-swizzled GLOBAL src
// + swizzled read. Slot key = ((row & 15) >> 1) & 3; row bases are 16-aligned.

// ---------------------------------------------------------------------------
// 128x128 tile core (kept for Mt + attention GEMMs): triple-buffered pipeline.
// ---------------------------------------------------------------------------
template<typename OutT>
__device__ __forceinline__ void gemm_tile128_pipe(
    const ushort_t* __restrict__ Ab, int lda,
    const ushort_t* __restrict__ Bb, int ldb,
    OutT* __restrict__ Cb, int ldc, int K,
    ushort_t* As, ushort_t* Bs)
{
    const int tid  = threadIdx.x;
    const int lane = tid & 63;
    const int w    = tid >> 6;
    const int l15 = lane & 15, l4 = lane >> 4;
    const int wr = w >> 1, wc = w & 1;
    const int srow = lane >> 2;
    const int scolsw = (((lane & 3) ^ ((srow >> 1) & 3)) * 8);
    const int l4s8 = (l4 ^ ((l15 >> 1) & 3)) * 8;
    const int nT = K >> 5;

    auto stage = [&](int t) {
        const int buf = t % 3;
        const int k0 = t * 32;
        #pragma unroll
        for (int i = 0; i < 2; ++i) {
            int r = w * 32 + i * 16;
            gload_lds16(Ab + (long)(r + srow) * lda + k0 + scolsw, &As[buf * 4096 + r * 32]);
            gload_lds16(Bb + (long)(r + srow) * ldb + k0 + scolsw, &Bs[buf * 4096 + r * 32]);
        }
    };

    f32x4 acc[4][4];
    #pragma unroll
    for (int m = 0; m < 4; ++m)
        #pragma unroll
        for (int n = 0; n < 4; ++n) acc[m][n] = (f32x4){0.f, 0.f, 0.f, 0.f};

    stage(0);
    if (nT > 1) stage(1);

    for (int t = 0; t < nT; ++t) {
        pipe_wait4(t + 1 >= nT);
        if (t + 2 < nT) stage(t + 2);
        const int buf = t % 3;

        bf16x8 af[4], bfv[4];
        #pragma unroll
        for (int m = 0; m < 4; ++m)
            af[m] = *(const bf16x8*)&As[buf * 4096 + (wr * 64 + m * 16 + l15) * 32 + l4s8];
        #pragma unroll
        for (int n = 0; n < 4; ++n)
            bfv[n] = *(const bf16x8*)&Bs[buf * 4096 + (wc * 64 + n * 16 + l15) * 32 + l4s8];
        #pragma unroll
        for (int m = 0; m < 4; ++m)
            #pragma unroll
            for (int n = 0; n < 4; ++n)
                acc[m][n] = __builtin_amdgcn_mfma_f32_16x16x32_bf16(af[m], bfv[n], acc[m][n], 0, 0, 0);
    }

    #pragma unroll
    for (int m = 0; m < 4; ++m)
        #pragma unroll
        for (int j = 0; j < 4; ++j) {
            long row = wr * 64 + m * 16 + l4 * 4 + j;
            #pragma unroll
            for (int n = 0; n < 4; ++n) {
                long col = wc * 64 + n * 16 + l15;
                if constexpr (std::is_same<OutT, float>::value)
                    Cb[row * ldc + col] = acc[m][n][j];
                else
                    Cb[row * ldc + col] = f2bf(acc[m][n][j]);
            }
        }
}

// Generic NT GEMM wrapper (2D grid; used for Mt)
template<typename OutT>
__global__ __launch_bounds__(256, 2) void gemm_bf16(
    const ushort_t* __restrict__ A, const ushort_t* __restrict__ B,
    OutT* __restrict__ C,
    int K, int lda, int ldb, int ldc)
{
    __shared__ ushort_t As[3 * 4096];
    __shared__ ushort_t Bs[3 * 4096];
    const ushort_t* Ab = A + (long)blockIdx.y * 128 * lda;
    const ushort_t* Bb = B + (long)blockIdx.x * 128 * ldb;
    OutT*           Cb = C + (long)blockIdx.y * 128 * ldc + (long)blockIdx.x * 128;
    gemm_tile128_pipe<OutT>(Ab, lda, Bb, ldb, Cb, ldc, K, As, Bs);
}

// ---------------------------------------------------------------------------
// 256x128 block tile (wave tile 128x64) split-output NT GEMM. 4 waves arranged
// 2(M) x 2(N). Raises FLOP/LDS-byte 1.5x vs 64x64 wave tile (LDS-BW bound fix).
// 1D grid + XCD-bijective swizzle (grid % 8 == 0).
// ---------------------------------------------------------------------------
__global__ __launch_bounds__(256, 2) void gemm_split256(
    const ushort_t* __restrict__ A, int lda, int K, int ntiles,
    const ushort_t* __restrict__ B,
    ushort_t* __restrict__ C1, int ldc1, int split,
    ushort_t* __restrict__ C2, int ldc2)
{
    __shared__ ushort_t As[3 * 8192];     // [3][256][32]
    __shared__ ushort_t Bs[3 * 4096];     // [3][128][32]
    const int id  = blockIdx.x;
    const int sid = (id & 7) * (gridDim.x >> 3) + (id >> 3);
    const int nt = sid % ntiles, mt = sid / ntiles;

    const int tid  = threadIdx.x;
    const int lane = tid & 63;
    const int w    = tid >> 6;
    const int l15 = lane & 15, l4 = lane >> 4;
    const int wm = w >> 1, wn = w & 1;    // wave tile: rows wm*128, cols wn*64
    const int srow = lane >> 2;
    const int scolsw = (((lane & 3) ^ ((srow >> 1) & 3)) * 8);
    const int l4s8 = (l4 ^ ((l15 >> 1) & 3)) * 8;
    const int nT = K >> 5;

    const ushort_t* Ab = A + (long)mt * 256 * lda;
    const ushort_t* Bb = B + (long)nt * 128 * K;

    auto stage = [&](int t) {
        const int buf = t % 3;
        const int k0 = t * 32;
        #pragma unroll
        for (int i = 0; i < 4; ++i) {     // A: wave covers rows w*64 + i*16
            int r = w * 64 + i * 16;
            gload_lds16(Ab + (long)(r + srow) * lda + k0 + scolsw, &As[buf * 8192 + r * 32]);
        }
        #pragma unroll
        for (int i = 0; i < 2; ++i) {     // B: wave covers rows w*32 + i*16
            int r = w * 32 + i * 16;
            gload_lds16(Bb + (long)(r + srow) * K + k0 + scolsw, &Bs[buf * 4096 + r * 32]);
        }
    };

    f32x4 acc[8][4];
    #pragma unroll
    for (int m = 0; m < 8; ++m)
        #pragma unroll
        for (int n = 0; n < 4; ++n) acc[m][n] = (f32x4){0.f, 0.f, 0.f, 0.f};

    stage(0);
    if (nT > 1) stage(1);

    for (int t = 0; t < nT; ++t) {
        pipe_wait6(t + 1 >= nT);
        if (t + 2 < nT) stage(t + 2);
        const int buf = t % 3;

        bf16x8 af[8], bfv[4];
        #pragma unroll
        for (int m = 0; m < 8; ++m)
            af[m] = *(const bf16x8*)&As[buf * 8192 + (wm * 128 + m * 16 + l15) * 32 + l4s8];
        #pragma unroll
        for (int n = 0; n < 4; ++n)
            bfv[n] = *(const bf16x8*)&Bs[buf * 4096 + (wn * 64 + n * 16 + l15) * 32 + l4s8];
        #pragma unroll
        for (int m = 0; m < 8; ++m)
            #pragma unroll
            for (int n = 0; n < 4; ++n)
                acc[m][n] = __builtin_amdgcn_mfma_f32_16x16x32_bf16(af[m], bfv[n], acc[m][n], 0, 0, 0);
    }

    // write-out: row = mt*256 + wm*128 + m*16 + l4*4 + j; col split at 128-tile
    ushort_t* Cb; int ldc; long colbase;
    if (nt < split) { Cb = C1; ldc = ldc1; colbase = (long)nt * 128; }
    else            { Cb = C2; ldc = ldc2; colbase = (long)(nt - split) * 128; }
    #pragma unroll
    for (int m = 0; m < 8; ++m)
        #pragma unroll
        for (int j = 0; j < 4; ++j) {
            long row = (long)mt * 256 + wm * 128 + m * 16 + l4 * 4 + j;
            #pragma unroll
            for (int n = 0; n < 4; ++n)
                Cb[row * ldc + colbase + wn * 64 + n * 16 + l15] = f2bf(acc[m][n][j]);
        }
}

// ---------------------------------------------------------------------------
// Phase A: S lower-triangle tiles, packed Spk[z][x][128][128]. K = 192.
// ---------------------------------------------------------------------------
__global__ __launch_bounds__(256, 2) void attn_s_gemm(
    const ushort_t* __restrict__ qnom, const ushort_t* __restrict__ qrb,
    const ushort_t* __restrict__ kabs, const ushort_t* __restrict__ kfull,
    ushort_t* __restrict__ Spk)
{
    __shared__ ushort_t As[3 * 4096];
    __shared__ ushort_t Bs[3 * 4096];
    const int id  = blockIdx.x;               // 0..2303
    const int sid = (id & 7) * 288 + (id >> 3);
    const int x = sid % 36, z = sid / 36;
    int ti = 0;
    while ((ti + 1) * (ti + 2) / 2 <= x) ++ti;
    const int si = x - ti * (ti + 1) / 2;
    const int h = z >> 2, b = z & 3;

    const int tid  = threadIdx.x;
    const int lane = tid & 63;
    const int w    = tid >> 6;
    const int l15 = lane & 15, l4 = lane >> 4;
    const int wr = w >> 1, wc = w & 1;
    const int srow = lane >> 2;
    const int scolsw = (((lane & 3) ^ ((srow >> 1) & 3)) * 8);
    const int l4s8 = (l4 ^ ((l15 >> 1) & 3)) * 8;

    const ushort_t* A1 = qnom + ((long)(b * 1024 + ti * 128)) * 2048 + h * 128;
    const ushort_t* A2 = qrb  + ((long)(b * 1024 + ti * 128)) * 1024 + h * 64;
    const ushort_t* B1 = kabs + ((long)(b * 1024 + si * 128)) * 2048 + h * 128;
    const ushort_t* B2 = kfull + ((long)(b * 1024 + si * 128)) * KLD + 512;
    ushort_t* Cb = Spk + (long)z * 589824 + (long)x * 16384;

    auto stage = [&](int t) {
        const int buf = t % 3;
        const ushort_t* Asrc; const ushort_t* Bsrc; int ldA, ldB;
        if (t < 4) { Asrc = A1 + t * 32;       Bsrc = B1 + t * 32;       ldA = 2048; ldB = 2048; }
        else       { Asrc = A2 + (t - 4) * 32; Bsrc = B2 + (t - 4) * 32; ldA = 1024; ldB = KLD; }
        #pragma unroll
        for (int i = 0; i < 2; ++i) {
            int r = w * 32 + i * 16;
            gload_lds16(Asrc + (long)(r + srow) * ldA + scolsw, &As[buf * 4096 + r * 32]);
            gload_lds16(Bsrc + (long)(r + srow) * ldB + scolsw, &Bs[buf * 4096 + r * 32]);
        }
    };

    f32x4 acc[4][4];
    #pragma unroll
    for (int m = 0; m < 4; ++m)
        #pragma unroll
        for (int n = 0; n < 4; ++n) acc[m][n] = (f32x4){0.f, 0.f, 0.f, 0.f};

    stage(0); stage(1);
    #pragma unroll
    for (int t = 0; t < 6; ++t) {
        pipe_wait4(t == 5);
        if (t + 2 < 6) stage(t + 2);
        const int buf = t % 3;
        bf16x8 af[4], bfv[4];
        #pragma unroll
        for (int m = 0; m < 4; ++m)
            af[m] = *(const bf16x8*)&As[buf * 4096 + (wr * 64 + m * 16 + l15) * 32 + l4s8];
        #pragma unroll
        for (int n = 0; n < 4; ++n)
            bfv[n] = *(const bf16x8*)&Bs[buf * 4096 + (wc * 64 + n * 16 + l15) * 32 + l4s8];
        #pragma unroll
        for (int m = 0; m < 4; ++m)
            #pragma unroll
            for (int n = 0; n < 4; ++n)
                acc[m][n] = __builtin_amdgcn_mfma_f32_16x16x32_bf16(af[m], bfv[n], acc[m][n], 0, 0, 0);
    }

    #pragma unroll
    for (int m = 0; m < 4; ++m)
        #pragma unroll
        for (int j = 0; j < 4; ++j) {
            long row = wr * 64 + m * 16 + l4 * 4 + j;
            #pragma unroll
            for (int n = 0; n < 4; ++n)
                Cb[row * 128 + wc * 64 + n * 16 + l15] = f2bf(acc[m][n][j]);
        }
}

// ---------------------------------------------------------------------------
// Phase B: in-place causal row softmax on packed S. One wave per q-row.
// ---------------------------------------------------------------------------
__global__ __launch_bounds__(256) void attn_softmax(ushort_t* __restrict__ Spk)
{
    const int wid  = threadIdx.x >> 6;
    const int lane = threadIdx.x & 63;
    const int r = blockIdx.x * 4 + wid;              // 0..65535
    const int z = r >> 10, t = r & 1023;
    const int ti = t >> 7;
    const int nc = ti + 1;                           // valid 128-col chunks
    ushort_t* base = Spk + (long)z * 589824 + (long)(ti * (ti + 1) / 2) * 16384
                        + (t & 127) * 128;
    const float SCL = ATT_SCALE * LOG2E;

    float p0[8], p1[8];
    float mx = -INFINITY;
    #pragma unroll
    for (int c = 0; c < 8; ++c) {
        p0[c] = -INFINITY; p1[c] = -INFINITY;
        if (c < nc) {
            uint_t u = *(const uint_t*)&base[c * 16384 + lane * 2];
            int kv = c * 128 + lane * 2;
            float a  = __uint_as_float(u << 16);
            float bb = __uint_as_float(u & 0xffff0000u);
            if (kv     <= t) p0[c] = a  * SCL;
            if (kv + 1 <= t) p1[c] = bb * SCL;
            mx = fmaxf(mx, fmaxf(p0[c], p1[c]));
        }
    }
    #pragma unroll
    for (int off = 32; off >= 1; off >>= 1) mx = fmaxf(mx, __shfl_xor(mx, off));
    float s = 0.f;
    #pragma unroll
    for (int c = 0; c < 8; ++c) {
        p0[c] = exp2f(p0[c] - mx);                   // -inf -> 0
        p1[c] = exp2f(p1[c] - mx);
        if (c < nc) s += p0[c] + p1[c];
    }
    #pragma unroll
    for (int off = 32; off >= 1; off >>= 1) s += __shfl_xor(s, off);
    const float inv = 1.f / s;
    #pragma unroll
    for (int c = 0; c < 8; ++c) if (c < nc) {
        uint_t o = (uint_t)f2bf(p0[c] * inv) | ((uint_t)f2bf(p1[c] * inv) << 16);
        *(uint_t*)&base[c * 16384 + lane * 2] = o;
    }
}

// ---------------------------------------------------------------------------
// Phase C: out[b, ti-rows, h*128..] = P @ VeffT_h^T (f32). 128-core pipeline.
// ---------------------------------------------------------------------------
__global__ __launch_bounds__(256, 2) void attn_pv_gemm(
    const ushort_t* __restrict__ Spk, const ushort_t* __restrict__ VeffT,
    float* __restrict__ out)
{
    __shared__ ushort_t As[3 * 4096];
    __shared__ ushort_t Bs[3 * 4096];
    const int id  = blockIdx.x;               // 0..511
    const int sid = (id & 7) * 64 + (id >> 3);
    const int ti = sid & 7, z = sid >> 3;
    const int tid  = threadIdx.x;
    const int lane = tid & 63;
    const int w    = tid >> 6;
    const int l15 = lane & 15, l4 = lane >> 4;
    const int wr = w >> 1, wc = w & 1;
    const int srow = lane >> 2;
    const int scolsw = (((lane & 3) ^ ((srow >> 1) & 3)) * 8);
    const int l4s8 = (l4 ^ ((l15 >> 1) & 3)) * 8;
    const int h = z >> 2, b = z & 3;
    const int nT = (ti + 1) * 4;              // K/32
    const ushort_t* Abase = Spk + (long)z * 589824 + (long)(ti * (ti + 1) / 2) * 16384;
    const ushort_t* Bb = VeffT + ((long)b * 2048 + h * 128) * 1024;
    float* Cb = out + ((long)b * 1024 + ti * 128) * 2048 + h * 128;

    auto stage = [&](int t) {
        const int buf = t % 3;
        const int k0 = t * 32;
        const ushort_t* At = Abase + (k0 >> 7) * 16384 + (k0 & 127);
        #pragma unroll
        for (int i = 0; i < 2; ++i) {
            int r = w * 32 + i * 16;
            gload_lds16(At + (long)(r + srow) * 128 + scolsw, &As[buf * 4096 + r * 32]);
            gload_lds16(Bb + (long)(r + srow) * 1024 + k0 + scolsw, &Bs[buf * 4096 + r * 32]);
        }
    };

    f32x4 acc[4][4];
    #pragma unroll
    for (int m = 0; m < 4; ++m)
        #pragma unroll
        for (int n = 0; n < 4; ++n) acc[m][n] = (f32x4){0.f, 0.f, 0.f, 0.f};

    stage(0); stage(1);
    for (int t = 0; t < nT; ++t) {
        pipe_wait4(t + 1 >= nT);
        if (t + 2 < nT) stage(t + 2);
        const int buf = t % 3;
        bf16x8 af[4], bfv[4];
        #pragma unroll
        for (int m = 0; m < 4; ++m)
            af[m] = *(const bf16x8*)&As[buf * 4096 + (wr * 64 + m * 16 + l15) * 32 + l4s8];
        #pragma unroll
        for (int n = 0; n < 4; ++n)
            bfv[n] = *(const bf16x8*)&Bs[buf * 4096 + (wc * 64 + n * 16 + l15) * 32 + l4s8];
        #pragma unroll
        for (int m = 0; m < 4; ++m)
            #pragma unroll
            for (int n = 0; n < 4; ++n)
                acc[m][n] = __builtin_amdgcn_mfma_f32_16x16x32_bf16(af[m], bfv[n], acc[m][n], 0, 0, 0);
    }

    #pragma unroll
    for (int m = 0; m < 4; ++m)
        #pragma unroll
        for (int j = 0; j < 4; ++j) {
            long row = wr * 64 + m * 16 + l4 * 4 + j;
            #pragma unroll
            for (int n = 0; n < 4; ++n)
                Cb[row * 2048 + wc * 64 + n * 16 + l15] = acc[m][n][j];
        }
}

// ---------------------------------------------------------------------------
// Fused f32->bf16 conversion. One block = 2048 contiguous elements.
// ---------------------------------------------------------------------------
__global__ void cvt_all(const float* __restrict__ x,   const float* __restrict__ Wdq,
                        const float* __restrict__ Wdkv, const float* __restrict__ Wkr,
                        const float* __restrict__ Wqr,  const float* __restrict__ Wo,
                        const float* __restrict__ Wuk,
                        ushort_t* __restrict__ xb, ushort_t* __restrict__ WB1,
                        ushort_t* __restrict__ WB2, ushort_t* __restrict__ Wo_b,
                        ushort_t* __restrict__ WB3)
{
    const int bid = blockIdx.x;
    const float* src = nullptr; ushort_t* dst;
    if      (bid < 4096) { src = x    + (long)bid * 2048;          dst = xb   + (long)bid * 2048; }
    else if (bid < 5632) { long b = bid - 4096; src = Wdq  + b * 2048; dst = WB1 + b * 2048; }
    else if (bid < 6144) { long b = bid - 5632; src = Wdkv + b * 2048; dst = WB1 + 3145728 + b * 2048; }
    else if (bid < 6208) { long b = bid - 6144; src = Wkr  + b * 2048; dst = WB1 + 4194304 + b * 2048; }
    else if (bid < 6272) { long b = bid - 6208;                        dst = WB1 + 4325376 + b * 2048; }
    else if (bid < 7040) { long b = bid - 6272; src = Wqr  + b * 2048; dst = WB2 + 3145728 + b * 2048; }
    else if (bid < 9088) { long b = bid - 7040; src = Wo   + b * 2048; dst = Wo_b + b * 2048; }
    else                 { long b = bid - 9088; src = Wuk  + b * 2048; dst = WB3 + b * 2048; }

    const long i = (long)threadIdx.x * 8;
    if (!src) { *(uint4*)&dst[i] = make_uint4(0, 0, 0, 0); return; }
    float4 a = *(const float4*)&src[i];
    float4 b4 = *(const float4*)&src[i + 4];
    ushort_t p[8] = {f2bf(a.x), f2bf(a.y), f2bf(a.z), f2bf(a.w),
                     f2bf(b4.x), f2bf(b4.y), f2bf(b4.z), f2bf(b4.w)};
    *(uint4*)&dst[i] = *(const uint4*)p;
}

// ---------------------------------------------------------------------------
// Generic transpose+convert: in [R][ldin] f32 -> out [ldin][R] bf16.
// ---------------------------------------------------------------------------
__global__ __launch_bounds__(256) void transcvt_g(
    const float* __restrict__ in, ushort_t* __restrict__ out, int ldin, int R)
{
    __shared__ float tile[64][65];
    const int c0 = blockIdx.x * 64, r0 = blockIdx.y * 64;
    const int t = threadIdx.x;
    #pragma unroll
    for (int i = 0; i < 4; ++i) {
        int idx = t + i * 256;
        int r = idx >> 4, c4 = idx & 15;
        float4 v = *(const float4*)&in[(long)(r0 + r) * ldin + c0 + c4 * 4];
        tile[r][c4 * 4 + 0] = v.x; tile[r][c4 * 4 + 1] = v.y;
        tile[r][c4 * 4 + 2] = v.z; tile[r][c4 * 4 + 3] = v.w;
    }
    __syncthreads();
    #pragma unroll
    for (int i = 0; i < 4; ++i) {
        int idx = t + i * 256;
        int c = idx >> 4, r4 = idx & 15;
        ushort_t p[4];
        #pragma unroll
        for (int j = 0; j < 4; ++j) p[j] = f2bf(tile[r4 * 4 + j][c]);
        *(uint2*)&out[(long)(c0 + c) * R + r0 + r4 * 4] = *(const uint2*)p;
    }
}

// ---------------------------------------------------------------------------
// RoPE kernels (both in-place, bf16)
// ---------------------------------------------------------------------------
__global__ void rope_kr_kernel(ushort_t* __restrict__ kfull,
                               const float* __restrict__ cosT, const float* __restrict__ sinT) {
    int p = blockIdx.x * 256 + threadIdx.x;          // BT*32 pairs
    if (p >= BT * 32) return;
    int bt = p >> 5, i = p & 31;
    int t = bt & (Tn - 1);
    float c = cosT[t * 32 + i], s = sinT[t * 32 + i];
    uint_t u = *(const uint_t*)&kfull[(long)bt * KLD + 512 + 2 * i];
    float re = __uint_as_float(u << 16);
    float im = __uint_as_float(u & 0xffff0000u);
    float o0 = re * c - im * s, o1 = re * s + im * c;
    uint_t o = (uint_t)f2bf(o0) | ((uint_t)f2bf(o1) << 16);
    *(uint_t*)&kfull[(long)bt * KLD + 512 + 2 * i] = o;
}

__global__ void rope_qr_kernel(ushort_t* __restrict__ qrb,
                               const float* __restrict__ cosT, const float* __restrict__ sinT) {
    int p = blockIdx.x * 256 + threadIdx.x;          // BT*NH*32 pairs
    if (p >= BT * 512) return;
    int bt = p >> 9, rem = p & 511;
    int hh = rem >> 5, i = rem & 31;
    int t = bt & (Tn - 1);
    float c = cosT[t * 32 + i], s = sinT[t * 32 + i];
    long off = (long)bt * 1024 + hh * 64 + 2 * i;
    uint_t u = *(const uint_t*)&qrb[off];
    float re = __uint_as_float(u << 16);
    float im = __uint_as_float(u & 0xffff0000u);
    float o0 = re * c - im * s, o1 = re * s + im * c;
    uint_t o = (uint_t)f2bf(o0) | ((uint_t)f2bf(o1) << 16);
    *(uint_t*)&qrb[off] = o;
}

// ---------------------------------------------------------------------------
// Transpose Veff [4096 bs][2048 hd] -> VeffT [4 b][2048 hd][1024 s] (bf16)
// ---------------------------------------------------------------------------
__global__ void transpose_veff(const ushort_t* __restrict__ Veff, ushort_t* __restrict__ VeffT) {
    int idx = blockIdx.x * 256 + threadIdx.x;        // 4*128*2048 = 1048576
    int c = idx & 2047, rest = idx >> 11;
    int t8 = rest & 127, b = rest >> 7;
    ushort_t v[8];
    #pragma unroll
    for (int j = 0; j < 8; ++j)
        v[j] = Veff[((long)b * Tn + t8 * 8 + j) * 2048 + c];
    *(uint4*)&VeffT[((long)b * 2048 + c) * Tn + t8 * 8] = *(const uint4*)v;
}

// ---------------------------------------------------------------------------
extern "C" void kernel_launch(void* const* d_in, const int* in_sizes, int n_in,
                              void* d_out, int out_size, void* d_ws, size_t ws_size,
                              hipStream_t stream)
{
    (void)in_sizes; (void)n_in; (void)out_size; (void)ws_size;
    const float* x     = (const float*)d_in[0];
    const float* cosT  = (const float*)d_in[1];
    const float* sinT  = (const float*)d_in[2];
    const float* W_dq  = (const float*)d_in[3];   // [1536][2048]
    const float* W_uq  = (const float*)d_in[4];   // [1536 q][2048 hd]
    const float* W_dkv = (const float*)d_in[5];   // [512][2048]
    const float* W_uk  = (const float*)d_in[6];   // [2048 hd][512 k] (NT-ready)
    const float* W_uv  = (const float*)d_in[7];   // [2048][512]
    const float* W_qr  = (const float*)d_in[8];   // [1024][1536]
    const float* W_kr  = (const float*)d_in[9];   // [64][2048]
    const float* W_o   = (const float*)d_in[10];  // [2048][2048]
    float* out = (float*)d_out;

    // ---- workspace: 71,565,312 ushorts = 143.1 MB ----
    ushort_t* ws = (ushort_t*)d_ws;
    ushort_t* xb     = ws;                              // 8388608
    ushort_t* WB1    = ws + 8388608;                    // 4456448  [2176][2048] = Wdq|Wdkv|Wkr|pad
    ushort_t* WB2    = ws + 12845056;                   // 4718592  [3072][1536] = WuqT|Wqr
    ushort_t* Wo_b   = ws + 17563648;                   // 4194304  [2048][2048]
    ushort_t* WuvT_b = ws + 21757952;                   // 1048576  [512][2048]
    ushort_t* cq_b   = ws + 22806528;                   // 6291456  [4096][1536] -> 29097984
    ushort_t* WB3    = ws + 29097984;                   // 2097152  [4096][512] = Wuk|Mt -> 31195136
    ushort_t* Veff   = ws + 31195136;                   // 8388608  (transient) -> 39583744
    ushort_t* Spk    = ws;                              // 37748736 [64 z][36][128][128]
    // PERSISTENT region:
    ushort_t* qnom   = ws + 39583744;                   // 8388608  [4096][2048]
    ushort_t* qr_b   = ws + 47972352;                   // 4194304  [4096][1024]
    ushort_t* kabs   = ws + 52166656;                   // 8388608  [4096][2048]
    ushort_t* kfull  = ws + 60555264;                   // 2621440  [4096][640]
    ushort_t* VeffT  = ws + 63176704;                   // 8388608  [4][2048][1024] -> 71565312
    ushort_t* Mtb    = WB3 + 1048576;                   // Mt output inside WB3

    dim3 blk(256, 1, 1);

    // ---- conversions (1 fused + 2 transposes) ----
    cvt_all<<<dim3(9600), blk, 0, stream>>>(x, W_dq, W_dkv, W_kr, W_qr, W_o, W_uk,
                                            xb, WB1, WB2, Wo_b, WB3);
    transcvt_g<<<dim3(32, 24), blk, 0, stream>>>(W_uq, WB2, 2048, 1536);      // WuqT
    transcvt_g<<<dim3(8, 32), blk, 0, stream>>>(W_uv, WuvT_b, 512, 2048);     // WuvT

    // ---- Mt = Wo @ WuvT^T -> WB3 rows 2048..4095 ----
    gemm_bf16<ushort_t><<<dim3(4, 16, 1), blk, 0, stream>>>(
        Wo_b, WuvT_b, Mtb, Cn, Cn, Cn, NLKV);

    // ---- group1: [c_q | c_kv|c_kr] = xb @ WB1^T  (N=2176, K=2048) ----
    gemm_split256<<<dim3(272), blk, 0, stream>>>(
        xb, Cn, Cn, 17, WB1, cq_b, NLQ, 12, kfull, KLD);
    rope_kr_kernel<<<dim3(BT*32/256), blk, 0, stream>>>(kfull, cosT, sinT);

    // ---- group2: [q_nom | c_qr] = cq_b @ WB2^T  (N=3072, K=1536) ----
    gemm_split256<<<dim3(384), blk, 0, stream>>>(
        cq_b, NLQ, NLQ, 24, WB2, qnom, Cn, 16, qr_b, NH*DHR);
    rope_qr_kernel<<<dim3(BT*512/256), blk, 0, stream>>>(qr_b, cosT, sinT);

    // ---- group3: [kabs | Veff] = c_kv @ WB3^T  (N=4096, K=512, A lda 640) ----
    gemm_split256<<<dim3(512), blk, 0, stream>>>(
        kfull, KLD, NLKV, 32, WB3, kabs, Cn, 16, Veff, Cn);
    transpose_veff<<<dim3(4096), blk, 0, stream>>>(Veff, VeffT);

    // ---- attention as GEMM phases (single-shot, 64 z) ----
    attn_s_gemm<<<dim3(2304), blk, 0, stream>>>(qnom, qr_b, kabs, kfull, Spk);
    attn_softmax<<<dim3(BT * NH / 4), blk, 0, stream>>>(Spk);
    attn_pv_gemm<<<dim3(512), blk, 0, stream>>>(Spk, VeffT, out);
}

// Round 17
// 270.512 us; speedup vs baseline: 1.2157x; 1.2157x over previous
//
#include <hip/hip_runtime.h>
#include <type_traits>

typedef unsigned short ushort_t;
typedef unsigned int   uint_t;
typedef __attribute__((ext_vector_type(8))) short bf16x8;
typedef __attribute__((ext_vector_type(4))) float f32x4;

constexpr int Bn = 4, Tn = 1024, Cn = 2048, NH = 16, HS = 128;
constexpr int NLQ = 1536, NLKV = 512, DHR = 64;
constexpr int BT = Bn * Tn;
constexpr int KLD = 640;                  // kfull leading dim (512 ckv + 64 kr + 64 pad)
constexpr float ATT_SCALE = 0.07216878364870323f; // 1/sqrt(192)
constexpr float LOG2E = 1.4426950408889634f;

__device__ __forceinline__ ushort_t f2bf(float f) {
    uint_t u = __float_as_uint(f);
    u += 0x7fffu + ((u >> 16) & 1u);   // RNE
    return (ushort_t)(u >> 16);
}

__device__ __forceinline__ void gload_lds16(const void* g, void* l) {
    __builtin_amdgcn_global_load_lds(
        (__attribute__((address_space(1))) void*)g,
        (__attribute__((address_space(3))) void*)l, 16, 0, 0);
}

// Pipeline sync (raw barrier, counted vmcnt — no implicit drain)
__device__ __forceinline__ void pipe_wait4(bool last) {
    if (last) asm volatile("s_waitcnt vmcnt(0)" ::: "memory");
    else      asm volatile("s_waitcnt vmcnt(4)" ::: "memory");
    __builtin_amdgcn_s_barrier();
    asm volatile("" ::: "memory");
}

// LDS swizzle (rule #21): linear gload_lds dest + inverse-swizzled GLOBAL src
// + swizzled read. Slot key = ((row & 15) >> 1) & 3; row bases are 16-aligned.

// ---------------------------------------------------------------------------
// 128x128 tile core: triple-buffered counted-vmcnt pipeline + swizzle (r15).
// ---------------------------------------------------------------------------
template<typename OutT>
__device__ __forceinline__ void gemm_tile128_pipe(
    const ushort_t* __restrict__ Ab, int lda,
    const ushort_t* __restrict__ Bb, int ldb,
    OutT* __restrict__ Cb, int ldc, int K,
    ushort_t* As, ushort_t* Bs)
{
    const int tid  = threadIdx.x;
    const int lane = tid & 63;
    const int w    = tid >> 6;
    const int l15 = lane & 15, l4 = lane >> 4;
    const int wr = w >> 1, wc = w & 1;
    const int srow = lane >> 2;
    const int scolsw = (((lane & 3) ^ ((srow >> 1) & 3)) * 8);
    const int l4s8 = (l4 ^ ((l15 >> 1) & 3)) * 8;
    const int nT = K >> 5;

    auto stage = [&](int t) {
        const int buf = t % 3;
        const int k0 = t * 32;
        #pragma unroll
        for (int i = 0; i < 2; ++i) {
            int r = w * 32 + i * 16;
            gload_lds16(Ab + (long)(r + srow) * lda + k0 + scolsw, &As[buf * 4096 + r * 32]);
            gload_lds16(Bb + (long)(r + srow) * ldb + k0 + scolsw, &Bs[buf * 4096 + r * 32]);
        }
    };

    f32x4 acc[4][4];
    #pragma unroll
    for (int m = 0; m < 4; ++m)
        #pragma unroll
        for (int n = 0; n < 4; ++n) acc[m][n] = (f32x4){0.f, 0.f, 0.f, 0.f};

    stage(0);
    if (nT > 1) stage(1);

    for (int t = 0; t < nT; ++t) {
        pipe_wait4(t + 1 >= nT);
        if (t + 2 < nT) stage(t + 2);
        const int buf = t % 3;

        bf16x8 af[4], bfv[4];
        #pragma unroll
        for (int m = 0; m < 4; ++m)
            af[m] = *(const bf16x8*)&As[buf * 4096 + (wr * 64 + m * 16 + l15) * 32 + l4s8];
        #pragma unroll
        for (int n = 0; n < 4; ++n)
            bfv[n] = *(const bf16x8*)&Bs[buf * 4096 + (wc * 64 + n * 16 + l15) * 32 + l4s8];
        #pragma unroll
        for (int m = 0; m < 4; ++m)
            #pragma unroll
            for (int n = 0; n < 4; ++n)
                acc[m][n] = __builtin_amdgcn_mfma_f32_16x16x32_bf16(af[m], bfv[n], acc[m][n], 0, 0, 0);
    }

    #pragma unroll
    for (int m = 0; m < 4; ++m)
        #pragma unroll
        for (int j = 0; j < 4; ++j) {
            long row = wr * 64 + m * 16 + l4 * 4 + j;
            #pragma unroll
            for (int n = 0; n < 4; ++n) {
                long col = wc * 64 + n * 16 + l15;
                if constexpr (std::is_same<OutT, float>::value)
                    Cb[row * ldc + col] = acc[m][n][j];
                else
                    Cb[row * ldc + col] = f2bf(acc[m][n][j]);
            }
        }
}

// ---------------------------------------------------------------------------
// group1 (split GEMM, 544 blocks) + Mt GEMM (64 tail blocks). Independent.
// ---------------------------------------------------------------------------
__global__ __launch_bounds__(256, 2) void g1_mt(
    const ushort_t* __restrict__ xb, const ushort_t* __restrict__ WB1,
    ushort_t* __restrict__ cq_b, ushort_t* __restrict__ kfull,
    const ushort_t* __restrict__ Wo_b, const ushort_t* __restrict__ WuvT_b,
    ushort_t* __restrict__ Mtb)
{
    __shared__ ushort_t As[3 * 4096];
    __shared__ ushort_t Bs[3 * 4096];
    const int id = blockIdx.x;
    if (id < 544) {
        const int sid = (id & 7) * 68 + (id >> 3);
        const int nt = sid % 17, mt = sid / 17;
        const ushort_t* Ab = xb + (long)mt * 128 * Cn;
        const ushort_t* Bb = WB1 + (long)nt * 128 * Cn;
        ushort_t* Cb; int ldc;
        if (nt < 12) { Cb = cq_b + (long)mt * 128 * NLQ + nt * 128;          ldc = NLQ; }
        else         { Cb = kfull + (long)mt * 128 * KLD + (nt - 12) * 128;  ldc = KLD; }
        gemm_tile128_pipe<ushort_t>(Ab, Cn, Bb, Cn, Cb, ldc, Cn, As, Bs);
    } else {
        const int local = id - 544;          // 0..63: Mt = Wo @ WuvT^T (2048x512 K=2048)
        const int mt = local >> 2, nt = local & 3;
        const ushort_t* Ab = Wo_b + (long)mt * 128 * Cn;
        const ushort_t* Bb = WuvT_b + (long)nt * 128 * Cn;
        ushort_t* Cb = Mtb + (long)mt * 128 * NLKV + nt * 128;
        gemm_tile128_pipe<ushort_t>(Ab, Cn, Bb, Cn, Cb, NLKV, Cn, As, Bs);
    }
}

// ---------------------------------------------------------------------------
// group2 (768 blocks) + rope_kr tail (512 blocks). Independent (kfull cols
// 512.. not touched by group2).
// ---------------------------------------------------------------------------
__global__ __launch_bounds__(256, 2) void g2_ropekr(
    const ushort_t* __restrict__ cq_b, const ushort_t* __restrict__ WB2,
    ushort_t* __restrict__ qnom, ushort_t* __restrict__ qr_b,
    ushort_t* __restrict__ kfull,
    const float* __restrict__ cosT, const float* __restrict__ sinT)
{
    __shared__ ushort_t As[3 * 4096];
    __shared__ ushort_t Bs[3 * 4096];
    const int id = blockIdx.x;
    if (id < 768) {
        const int sid = (id & 7) * 96 + (id >> 3);
        const int nt = sid % 24, mt = sid / 24;
        const ushort_t* Ab = cq_b + (long)mt * 128 * NLQ;
        const ushort_t* Bb = WB2 + (long)nt * 128 * NLQ;
        ushort_t* Cb; int ldc;
        if (nt < 16) { Cb = qnom + (long)mt * 128 * Cn + nt * 128;               ldc = Cn; }
        else         { Cb = qr_b + (long)mt * 128 * (NH*DHR) + (nt - 16) * 128;  ldc = NH*DHR; }
        gemm_tile128_pipe<ushort_t>(Ab, NLQ, Bb, NLQ, Cb, ldc, NLQ, As, Bs);
    } else {
        int p = (id - 768) * 256 + threadIdx.x;      // BT*32 pairs
        if (p >= BT * 32) return;
        int bt = p >> 5, i = p & 31;
        int t = bt & (Tn - 1);
        float c = cosT[t * 32 + i], s = sinT[t * 32 + i];
        uint_t u = *(const uint_t*)&kfull[(long)bt * KLD + 512 + 2 * i];
        float re = __uint_as_float(u << 16);
        float im = __uint_as_float(u & 0xffff0000u);
        float o0 = re * c - im * s, o1 = re * s + im * c;
        uint_t o = (uint_t)f2bf(o0) | ((uint_t)f2bf(o1) << 16);
        *(uint_t*)&kfull[(long)bt * KLD + 512 + 2 * i] = o;
    }
}

// ---------------------------------------------------------------------------
// group3 (1024 blocks) + rope_qr tail (8192 blocks). Independent (qr_b not
// touched by group3).
// ---------------------------------------------------------------------------
__global__ __launch_bounds__(256, 2) void g3_ropeqr(
    const ushort_t* __restrict__ kfull, const ushort_t* __restrict__ WB3,
    ushort_t* __restrict__ kabs, ushort_t* __restrict__ Veff,
    ushort_t* __restrict__ qr_b,
    const float* __restrict__ cosT, const float* __restrict__ sinT)
{
    __shared__ ushort_t As[3 * 4096];
    __shared__ ushort_t Bs[3 * 4096];
    const int id = blockIdx.x;
    if (id < 1024) {
        const int sid = (id & 7) * 128 + (id >> 3);
        const int nt = sid % 32, mt = sid / 32;
        const ushort_t* Ab = kfull + (long)mt * 128 * KLD;
        const ushort_t* Bb = WB3 + (long)nt * 128 * NLKV;
        ushort_t* Cb; long coff;
        if (nt < 16) { Cb = kabs; coff = nt * 128; }
        else         { Cb = Veff; coff = (nt - 16) * 128; }
        gemm_tile128_pipe<ushort_t>(Ab, KLD, Bb, NLKV,
                                    Cb + (long)mt * 128 * Cn + coff, Cn, NLKV, As, Bs);
    } else {
        int p = (id - 1024) * 256 + threadIdx.x;     // BT*NH*32 pairs
        if (p >= BT * 512) return;
        int bt = p >> 9, rem = p & 511;
        int hh = rem >> 5, i = rem & 31;
        int t = bt & (Tn - 1);
        float c = cosT[t * 32 + i], s = sinT[t * 32 + i];
        long off = (long)bt * 1024 + hh * 64 + 2 * i;
        uint_t u = *(const uint_t*)&qr_b[off];
        float re = __uint_as_float(u << 16);
        float im = __uint_as_float(u & 0xffff0000u);
        float o0 = re * c - im * s, o1 = re * s + im * c;
        uint_t o = (uint_t)f2bf(o0) | ((uint_t)f2bf(o1) << 16);
        *(uint_t*)&qr_b[off] = o;
    }
}

// ---------------------------------------------------------------------------
// attn_s (2304 blocks) + transpose_veff tail (4096 blocks). Independent
// (Veff moved out of Spk's alias range).
// ---------------------------------------------------------------------------
__global__ __launch_bounds__(256, 2) void attn_s_tv(
    const ushort_t* __restrict__ qnom, const ushort_t* __restrict__ qrb,
    const ushort_t* __restrict__ kabs, const ushort_t* __restrict__ kfull,
    ushort_t* __restrict__ Spk,
    const ushort_t* __restrict__ Veff, ushort_t* __restrict__ VeffT)
{
    __shared__ ushort_t As[3 * 4096];
    __shared__ ushort_t Bs[3 * 4096];
    const int id = blockIdx.x;
    if (id >= 2304) {                         // transpose_veff
        int idx = (id - 2304) * 256 + threadIdx.x;   // 4*128*2048
        int c = idx & 2047, rest = idx >> 11;
        int t8 = rest & 127, b = rest >> 7;
        ushort_t v[8];
        #pragma unroll
        for (int j = 0; j < 8; ++j)
            v[j] = Veff[((long)b * Tn + t8 * 8 + j) * 2048 + c];
        *(uint4*)&VeffT[((long)b * 2048 + c) * Tn + t8 * 8] = *(const uint4*)v;
        return;
    }
    const int sid = (id & 7) * 288 + (id >> 3);
    const int x = sid % 36, z = sid / 36;
    int ti = 0;
    while ((ti + 1) * (ti + 2) / 2 <= x) ++ti;
    const int si = x - ti * (ti + 1) / 2;
    const int h = z >> 2, b = z & 3;

    const int tid  = threadIdx.x;
    const int lane = tid & 63;
    const int w    = tid >> 6;
    const int l15 = lane & 15, l4 = lane >> 4;
    const int wr = w >> 1, wc = w & 1;
    const int srow = lane >> 2;
    const int scolsw = (((lane & 3) ^ ((srow >> 1) & 3)) * 8);
    const int l4s8 = (l4 ^ ((l15 >> 1) & 3)) * 8;

    const ushort_t* A1 = qnom + ((long)(b * 1024 + ti * 128)) * 2048 + h * 128;
    const ushort_t* A2 = qrb  + ((long)(b * 1024 + ti * 128)) * 1024 + h * 64;
    const ushort_t* B1 = kabs + ((long)(b * 1024 + si * 128)) * 2048 + h * 128;
    const ushort_t* B2 = kfull + ((long)(b * 1024 + si * 128)) * KLD + 512;
    ushort_t* Cb = Spk + (long)z * 589824 + (long)x * 16384;

    auto stage = [&](int t) {
        const int buf = t % 3;
        const ushort_t* Asrc; const ushort_t* Bsrc; int ldA, ldB;
        if (t < 4) { Asrc = A1 + t * 32;       Bsrc = B1 + t * 32;       ldA = 2048; ldB = 2048; }
        else       { Asrc = A2 + (t - 4) * 32; Bsrc = B2 + (t - 4) * 32; ldA = 1024; ldB = KLD; }
        #pragma unroll
        for (int i = 0; i < 2; ++i) {
            int r = w * 32 + i * 16;
            gload_lds16(Asrc + (long)(r + srow) * ldA + scolsw, &As[buf * 4096 + r * 32]);
            gload_lds16(Bsrc + (long)(r + srow) * ldB + scolsw, &Bs[buf * 4096 + r * 32]);
        }
    };

    f32x4 acc[4][4];
    #pragma unroll
    for (int m = 0; m < 4; ++m)
        #pragma unroll
        for (int n = 0; n < 4; ++n) acc[m][n] = (f32x4){0.f, 0.f, 0.f, 0.f};

    stage(0); stage(1);
    #pragma unroll
    for (int t = 0; t < 6; ++t) {
        pipe_wait4(t == 5);
        if (t + 2 < 6) stage(t + 2);
        const int buf = t % 3;
        bf16x8 af[4], bfv[4];
        #pragma unroll
        for (int m = 0; m < 4; ++m)
            af[m] = *(const bf16x8*)&As[buf * 4096 + (wr * 64 + m * 16 + l15) * 32 + l4s8];
        #pragma unroll
        for (int n = 0; n < 4; ++n)
            bfv[n] = *(const bf16x8*)&Bs[buf * 4096 + (wc * 64 + n * 16 + l15) * 32 + l4s8];
        #pragma unroll
        for (int m = 0; m < 4; ++m)
            #pragma unroll
            for (int n = 0; n < 4; ++n)
                acc[m][n] = __builtin_amdgcn_mfma_f32_16x16x32_bf16(af[m], bfv[n], acc[m][n], 0, 0, 0);
    }

    #pragma unroll
    for (int m = 0; m < 4; ++m)
        #pragma unroll
        for (int j = 0; j < 4; ++j) {
            long row = wr * 64 + m * 16 + l4 * 4 + j;
            #pragma unroll
            for (int n = 0; n < 4; ++n)
                Cb[row * 128 + wc * 64 + n * 16 + l15] = f2bf(acc[m][n][j]);
        }
}

// ---------------------------------------------------------------------------
// Causal row softmax on packed S (in-place). One wave per q-row.
// ---------------------------------------------------------------------------
__global__ __launch_bounds__(256) void attn_softmax(ushort_t* __restrict__ Spk)
{
    const int wid  = threadIdx.x >> 6;
    const int lane = threadIdx.x & 63;
    const int r = blockIdx.x * 4 + wid;              // 0..65535
    const int z = r >> 10, t = r & 1023;
    const int ti = t >> 7;
    const int nc = ti + 1;
    ushort_t* base = Spk + (long)z * 589824 + (long)(ti * (ti + 1) / 2) * 16384
                        + (t & 127) * 128;
    const float SCL = ATT_SCALE * LOG2E;

    float p0[8], p1[8];
    float mx = -INFINITY;
    #pragma unroll
    for (int c = 0; c < 8; ++c) {
        p0[c] = -INFINITY; p1[c] = -INFINITY;
        if (c < nc) {
            uint_t u = *(const uint_t*)&base[c * 16384 + lane * 2];
            int kv = c * 128 + lane * 2;
            float a  = __uint_as_float(u << 16);
            float bb = __uint_as_float(u & 0xffff0000u);
            if (kv     <= t) p0[c] = a  * SCL;
            if (kv + 1 <= t) p1[c] = bb * SCL;
            mx = fmaxf(mx, fmaxf(p0[c], p1[c]));
        }
    }
    #pragma unroll
    for (int off = 32; off >= 1; off >>= 1) mx = fmaxf(mx, __shfl_xor(mx, off));
    float s = 0.f;
    #pragma unroll
    for (int c = 0; c < 8; ++c) {
        p0[c] = exp2f(p0[c] - mx);
        p1[c] = exp2f(p1[c] - mx);
        if (c < nc) s += p0[c] + p1[c];
    }
    #pragma unroll
    for (int off = 32; off >= 1; off >>= 1) s += __shfl_xor(s, off);
    const float inv = 1.f / s;
    #pragma unroll
    for (int c = 0; c < 8; ++c) if (c < nc) {
        uint_t o = (uint_t)f2bf(p0[c] * inv) | ((uint_t)f2bf(p1[c] * inv) << 16);
        *(uint_t*)&base[c * 16384 + lane * 2] = o;
    }
}

// ---------------------------------------------------------------------------
// attn_pv: out = P @ VeffT_h^T (f32), 512 blocks + XCD swizzle.
// ---------------------------------------------------------------------------
__global__ __launch_bounds__(256, 2) void attn_pv_gemm(
    const ushort_t* __restrict__ Spk, const ushort_t* __restrict__ VeffT,
    float* __restrict__ out)
{
    __shared__ ushort_t As[3 * 4096];
    __shared__ ushort_t Bs[3 * 4096];
    const int id  = blockIdx.x;
    const int sid = (id & 7) * 64 + (id >> 3);
    const int ti = sid & 7, z = sid >> 3;
    const int tid  = threadIdx.x;
    const int lane = tid & 63;
    const int w    = tid >> 6;
    const int l15 = lane & 15, l4 = lane >> 4;
    const int wr = w >> 1, wc = w & 1;
    const int srow = lane >> 2;
    const int scolsw = (((lane & 3) ^ ((srow >> 1) & 3)) * 8);
    const int l4s8 = (l4 ^ ((l15 >> 1) & 3)) * 8;
    const int h = z >> 2, b = z & 3;
    const int nT = (ti + 1) * 4;
    const ushort_t* Abase = Spk + (long)z * 589824 + (long)(ti * (ti + 1) / 2) * 16384;
    const ushort_t* Bb = VeffT + ((long)b * 2048 + h * 128) * 1024;
    float* Cb = out + ((long)b * 1024 + ti * 128) * 2048 + h * 128;

    auto stage = [&](int t) {
        const int buf = t % 3;
        const int k0 = t * 32;
        const ushort_t* At = Abase + (k0 >> 7) * 16384 + (k0 & 127);
        #pragma unroll
        for (int i = 0; i < 2; ++i) {
            int r = w * 32 + i * 16;
            gload_lds16(At + (long)(r + srow) * 128 + scolsw, &As[buf * 4096 + r * 32]);
            gload_lds16(Bb + (long)(r + srow) * 1024 + k0 + scolsw, &Bs[buf * 4096 + r * 32]);
        }
    };

    f32x4 acc[4][4];
    #pragma unroll
    for (int m = 0; m < 4; ++m)
        #pragma unroll
        for (int n = 0; n < 4; ++n) acc[m][n] = (f32x4){0.f, 0.f, 0.f, 0.f};

    stage(0); stage(1);
    for (int t = 0; t < nT; ++t) {
        pipe_wait4(t + 1 >= nT);
        if (t + 2 < nT) stage(t + 2);
        const int buf = t % 3;
        bf16x8 af[4], bfv[4];
        #pragma unroll
        for (int m = 0; m < 4; ++m)
            af[m] = *(const bf16x8*)&As[buf * 4096 + (wr * 64 + m * 16 + l15) * 32 + l4s8];
        #pragma unroll
        for (int n = 0; n < 4; ++n)
            bfv[n] = *(const bf16x8*)&Bs[buf * 4096 + (wc * 64 + n * 16 + l15) * 32 + l4s8];
        #pragma unroll
        for (int m = 0; m < 4; ++m)
            #pragma unroll
            for (int n = 0; n < 4; ++n)
                acc[m][n] = __builtin_amdgcn_mfma_f32_16x16x32_bf16(af[m], bfv[n], acc[m][n], 0, 0, 0);
    }

    #pragma unroll
    for (int m = 0; m < 4; ++m)
        #pragma unroll
        for (int j = 0; j < 4; ++j) {
            long row = wr * 64 + m * 16 + l4 * 4 + j;
            #pragma unroll
            for (int n = 0; n < 4; ++n)
                Cb[row * 2048 + wc * 64 + n * 16 + l15] = acc[m][n][j];
        }
}

// ---------------------------------------------------------------------------
// prep_all: fused conversions + transposes (range dispatch).
// blocks 0..9599: cvt ranges; 9600..10367: Wuq transpose; 10368..10623: Wuv.
// ---------------------------------------------------------------------------
__global__ __launch_bounds__(256) void prep_all(
    const float* __restrict__ x,    const float* __restrict__ Wdq,
    const float* __restrict__ Wdkv, const float* __restrict__ Wkr,
    const float* __restrict__ Wqr,  const float* __restrict__ Wo,
    const float* __restrict__ Wuk,  const float* __restrict__ Wuq,
    const float* __restrict__ Wuv,
    ushort_t* __restrict__ xb, ushort_t* __restrict__ WB1,
    ushort_t* __restrict__ WB2, ushort_t* __restrict__ Wo_b,
    ushort_t* __restrict__ WB3, ushort_t* __restrict__ WuvT_b)
{
    const int bid = blockIdx.x;
    const int t = threadIdx.x;

    if (bid >= 9600) {                        // transpose+convert branches
        __shared__ float tile[64][65];
        const float* in; ushort_t* outp; int ldin, R, c0, r0;
        if (bid < 10368) { int l = bid - 9600;  in = Wuq; outp = WB2;    ldin = 2048; R = 1536; c0 = (l % 32) * 64; r0 = (l / 32) * 64; }
        else             { int l = bid - 10368; in = Wuv; outp = WuvT_b; ldin = 512;  R = 2048; c0 = (l % 8) * 64;  r0 = (l / 8) * 64; }
        #pragma unroll
        for (int i = 0; i < 4; ++i) {
            int idx = t + i * 256;
            int r = idx >> 4, c4 = idx & 15;
            float4 v = *(const float4*)&in[(long)(r0 + r) * ldin + c0 + c4 * 4];
            tile[r][c4 * 4 + 0] = v.x; tile[r][c4 * 4 + 1] = v.y;
            tile[r][c4 * 4 + 2] = v.z; tile[r][c4 * 4 + 3] = v.w;
        }
        __syncthreads();
        #pragma unroll
        for (int i = 0; i < 4; ++i) {
            int idx = t + i * 256;
            int c = idx >> 4, r4 = idx & 15;
            ushort_t p[4];
            #pragma unroll
            for (int j = 0; j < 4; ++j) p[j] = f2bf(tile[r4 * 4 + j][c]);
            *(uint2*)&outp[(long)(c0 + c) * R + r0 + r4 * 4] = *(const uint2*)p;
        }
        return;
    }

    const float* src = nullptr; ushort_t* dst;
    if      (bid < 4096) { src = x    + (long)bid * 2048;          dst = xb   + (long)bid * 2048; }
    else if (bid < 5632) { long b = bid - 4096; src = Wdq  + b * 2048; dst = WB1 + b * 2048; }
    else if (bid < 6144) { long b = bid - 5632; src = Wdkv + b * 2048; dst = WB1 + 3145728 + b * 2048; }
    else if (bid < 6208) { long b = bid - 6144; src = Wkr  + b * 2048; dst = WB1 + 4194304 + b * 2048; }
    else if (bid < 6272) { long b = bid - 6208;                        dst = WB1 + 4325376 + b * 2048; }
    else if (bid < 7040) { long b = bid - 6272; src = Wqr  + b * 2048; dst = WB2 + 3145728 + b * 2048; }
    else if (bid < 9088) { long b = bid - 7040; src = Wo   + b * 2048; dst = Wo_b + b * 2048; }
    else                 { long b = bid - 9088; src = Wuk  + b * 2048; dst = WB3 + b * 2048; }

    const long i = (long)t * 8;
    if (!src) { *(uint4*)&dst[i] = make_uint4(0, 0, 0, 0); return; }
    float4 a = *(const float4*)&src[i];
    float4 b4 = *(const float4*)&src[i + 4];
    ushort_t p[8] = {f2bf(a.x), f2bf(a.y), f2bf(a.z), f2bf(a.w),
                     f2bf(b4.x), f2bf(b4.y), f2bf(b4.z), f2bf(b4.w)};
    *(uint4*)&dst[i] = *(const uint4*)p;
}

// ---------------------------------------------------------------------------
extern "C" void kernel_launch(void* const* d_in, const int* in_sizes, int n_in,
                              void* d_out, int out_size, void* d_ws, size_t ws_size,
                              hipStream_t stream)
{
    (void)in_sizes; (void)n_in; (void)out_size; (void)ws_size;
    const float* x     = (const float*)d_in[0];
    const float* cosT  = (const float*)d_in[1];
    const float* sinT  = (const float*)d_in[2];
    const float* W_dq  = (const float*)d_in[3];
    const float* W_uq  = (const float*)d_in[4];
    const float* W_dkv = (const float*)d_in[5];
    const float* W_uk  = (const float*)d_in[6];
    const float* W_uv  = (const float*)d_in[7];
    const float* W_qr  = (const float*)d_in[8];
    const float* W_kr  = (const float*)d_in[9];
    const float* W_o   = (const float*)d_in[10];
    float* out = (float*)d_out;

    // ---- workspace: 79,953,920 ushorts = 159.9 MB (<= proven 180.9 MB) ----
    // Veff moved ABOVE the old end: it is read by transpose_veff concurrently
    // with attn_s writing Spk (which aliases the low scratch region).
    ushort_t* ws = (ushort_t*)d_ws;
    ushort_t* xb     = ws;                              // 8388608
    ushort_t* WB1    = ws + 8388608;                    // 4456448  [2176][2048]
    ushort_t* WB2    = ws + 12845056;                   // 4718592  [3072][1536] = WuqT|Wqr
    ushort_t* Wo_b   = ws + 17563648;                   // 4194304  [2048][2048]
    ushort_t* WuvT_b = ws + 21757952;                   // 1048576  [512][2048]
    ushort_t* cq_b   = ws + 22806528;                   // 6291456  [4096][1536]
    ushort_t* WB3    = ws + 29097984;                   // 2097152  [4096][512] = Wuk|Mt
    ushort_t* Spk    = ws;                              // 37748736 [64 z][36][128][128]
    // PERSISTENT:
    ushort_t* qnom   = ws + 39583744;                   // 8388608
    ushort_t* qr_b   = ws + 47972352;                   // 4194304
    ushort_t* kabs   = ws + 52166656;                   // 8388608
    ushort_t* kfull  = ws + 60555264;                   // 2621440  [4096][640]
    ushort_t* VeffT  = ws + 63176704;                   // 8388608  [4][2048][1024]
    ushort_t* Veff   = ws + 71565312;                   // 8388608  (lives past attn_s)
    ushort_t* Mtb    = WB3 + 1048576;

    dim3 blk(256, 1, 1);

    // 1) conversions + transposes (fused)
    prep_all<<<dim3(10624), blk, 0, stream>>>(
        x, W_dq, W_dkv, W_kr, W_qr, W_o, W_uk, W_uq, W_uv,
        xb, WB1, WB2, Wo_b, WB3, WuvT_b);

    // 2) group1 [c_q | c_kv|c_kr] (544) + Mt (64)
    g1_mt<<<dim3(608), blk, 0, stream>>>(xb, WB1, cq_b, kfull, Wo_b, WuvT_b, Mtb);

    // 3) group2 [q_nom | c_qr] (768) + rope_kr (512)
    g2_ropekr<<<dim3(1280), blk, 0, stream>>>(cq_b, WB2, qnom, qr_b, kfull, cosT, sinT);

    // 4) group3 [kabs | Veff] (1024) + rope_qr (8192)
    g3_ropeqr<<<dim3(9216), blk, 0, stream>>>(kfull, WB3, kabs, Veff, qr_b, cosT, sinT);

    // 5) attn_s (2304) + transpose_veff (4096)
    attn_s_tv<<<dim3(6400), blk, 0, stream>>>(qnom, qr_b, kabs, kfull, Spk, Veff, VeffT);

    // 6) softmax
    attn_softmax<<<dim3(BT * NH / 4), blk, 0, stream>>>(Spk);

    // 7) PV -> out
    attn_pv_gemm<<<dim3(512), blk, 0, stream>>>(Spk, VeffT, out);
}